// Round 9
// baseline (607.028 us; speedup 1.0000x reference)
//
#include <hip/hip_runtime.h>
#include <cstdint>

#define NROW 6144
#define KDIM 128
#define NLAB 200
#define C_COEF (-0.28719499063341177f)   /* -ln(99)/16 ; A_COEF = 2 exactly */
#define UBV 64.0f
#define BCAP 768

typedef _Float16 f16x8 __attribute__((ext_vector_type(8)));
typedef float f32x4 __attribute__((ext_vector_type(4)));
typedef __attribute__((address_space(1))) const void as1c_void;
typedef __attribute__((address_space(3))) void as3_void;

__device__ __forceinline__ float softplus_f(float x){
  return fmaxf(x, 0.f) + __logf(1.f + __expf(-fabsf(x)));
}
__device__ __forceinline__ float waveAllRedF(float v){
#pragma unroll
  for (int o = 32; o; o >>= 1) v += __shfl_down(v, o, 64);
  return __shfl(v, 0, 64);
}
__device__ __forceinline__ int waveAllRedI(int v){
#pragma unroll
  for (int o = 32; o; o >>= 1) v += __shfl_down(v, o, 64);
  return __shfl(v, 0, 64);
}
__device__ __forceinline__ unsigned key16_of(_Float16 h){
  unsigned short b = __builtin_bit_cast(unsigned short, h);
  return (b & 0x8000u) ? (unsigned)((unsigned short)~b) : (unsigned)(b | 0x8000u);
}
__device__ __forceinline__ float key16_dec(unsigned k){
  unsigned short b = (k & 0x8000u) ? (unsigned short)(k & 0x7FFFu)
                                   : (unsigned short)(~k & 0xFFFFu);
  return (float)__builtin_bit_cast(_Float16, b);
}

// ---------------- labels + per-label histogram + member lists ----------------
__global__ void k_label(const int* __restrict__ y, unsigned char* __restrict__ lab,
                        int* __restrict__ cnt, int* __restrict__ simIdx){
  const int row = blockIdx.x;
  const int t = threadIdx.x;
  if (t < NLAB){
    if (y[(size_t)row * NLAB + t] != 0){
      lab[row] = (unsigned char)t;
      int p = atomicAdd(&cnt[t], 1);
      if (p < 512) simIdx[t * 512 + p] = row;
    }
  }
}

// ---------------- tanh -> swizzled f16, + quantization-loss partial ----------------
__global__ __launch_bounds__(256) void k_tanh(const float* __restrict__ u,
    _Float16* __restrict__ uhswz, float* __restrict__ accf){
  const int tid = threadIdx.x;
  const int gid = blockIdx.x * 256 + tid;
  const int row = gid >> 4;
  const int h = gid & 15;
  const int g = h ^ (row & 7);
  const float* sp = u + (size_t)row * KDIM + g * 8;
  float q = 0.f;
  f16x8 o;
#pragma unroll
  for (int t = 0; t < 8; t++){
    float x = sp[t];
    float e2 = __expf(2.f * x);
    float th = 1.f - 2.f * __builtin_amdgcn_rcpf(e2 + 1.f);
    float sg = (th > 0.f) ? 1.f : ((th < 0.f) ? -1.f : 0.f);
    float d = th - sg;
    q += d * d;
    o[t] = (_Float16)th;
  }
  *(f16x8*)(uhswz + (size_t)row * KDIM + h * 8) = o;
  q = waveAllRedF(q);
  __shared__ float qb[4];
  if ((tid & 63) == 0) qb[tid >> 6] = q;
  __syncthreads();
  if (tid == 0) atomicAdd(&accf[0], qb[0] + qb[1] + qb[2] + qb[3]);
}

// ------- inner = uh @ uh^T -> f16 out; epilogue also emits per-row sum & sum^2 -------
__global__ __launch_bounds__(256) void k_mm(const _Float16* __restrict__ A,
    _Float16* __restrict__ out, float* __restrict__ rowSum,
    float* __restrict__ rowSum2){
  __shared__ __align__(16) _Float16 SH[2 * 128 * KDIM];
  _Float16* As = SH;
  _Float16* Bs = SH + 128 * KDIM;
  const int tid = threadIdx.x;
  const int wav = tid >> 6, lane = tid & 63;
  const int bj = blockIdx.x, bi = blockIdx.y;

  const char* Ag = (const char*)(A + (size_t)(bi * 128) * KDIM);
  const char* Bg = (const char*)(A + (size_t)(bj * 128) * KDIM);
  char* Asb = (char*)As;
  char* Bsb = (char*)Bs;
#pragma unroll
  for (int t = 0; t < 8; t++){
    const int ub = wav * 8192 + t * 1024;
    __builtin_amdgcn_global_load_lds((as1c_void*)(Ag + ub + lane * 16),
                                     (as3_void*)(Asb + ub), 16, 0, 0);
    __builtin_amdgcn_global_load_lds((as1c_void*)(Bg + ub + lane * 16),
                                     (as3_void*)(Bsb + ub), 16, 0, 0);
  }
  __syncthreads();

  const int quad = lane >> 4, l16 = lane & 15;
  const int wm = (wav >> 1) * 64, wn = (wav & 1) * 64;
  f32x4 acc[4][4];
#pragma unroll
  for (int im = 0; im < 4; im++)
#pragma unroll
    for (int in = 0; in < 4; in++)
      acc[im][in] = (f32x4){0.f, 0.f, 0.f, 0.f};

#pragma unroll
  for (int kb = 0; kb < 4; kb++){
    f16x8 af[4], bf[4];
#pragma unroll
    for (int i = 0; i < 4; i++){
      const int m = wm + i * 16 + l16;
      const int gidx = kb * 4 + quad;
      af[i] = *(const f16x8*)(Asb + m * 256 + ((gidx ^ (m & 7)) << 4));
      const int n = wn + i * 16 + l16;
      bf[i] = *(const f16x8*)(Bsb + n * 256 + ((gidx ^ (n & 7)) << 4));
    }
#pragma unroll
    for (int im = 0; im < 4; im++)
#pragma unroll
      for (int in = 0; in < 4; in++)
        acc[im][in] = __builtin_amdgcn_mfma_f32_16x16x32_f16(af[im], bf[in], acc[im][in], 0, 0, 0);
  }
  __syncthreads();

  _Float16* Cs = SH;
#pragma unroll
  for (int im = 0; im < 4; im++)
#pragma unroll
    for (int in = 0; in < 4; in++)
#pragma unroll
      for (int r = 0; r < 4; r++){
        const int rl = wm + im * 16 + quad * 4 + r;
        const int cl = wn + in * 16 + l16;
        Cs[rl * 132 + cl] = (_Float16)acc[im][in][r];
      }
  __syncthreads();

  _Float16* obase = out + (size_t)(bi * 128) * NROW + (size_t)bj * 128;
  const int s = tid & 15;
#pragma unroll
  for (int i = 0; i < 8; i++){
    const int r = (tid >> 4) + i * 16;
    f16x8 vv = *(const f16x8*)(Cs + r * 132 + s * 8);
    *(f16x8*)(obase + (size_t)r * NROW + s * 8) = vv;
    // per-row partial sums over this 128-col slice (f16-rounded values)
    float a = 0.f, b = 0.f;
#pragma unroll
    for (int e = 0; e < 8; e++){
      float x = (float)vv[e];
      a += x; b += x * x;
    }
#pragma unroll
    for (int o = 8; o; o >>= 1){
      a += __shfl_down(a, o, 16);
      b += __shfl_down(b, o, 16);
    }
    if (s == 0){
      atomicAdd(&rowSum[bi * 128 + r], a);
      atomicAdd(&rowSum2[bi * 128 + r], b);
    }
  }
}

// -------- k_band: wave-per-row, ONE sweep. tau bracket + band compaction --------
// No LDS, no barriers. tau1/tau2 from rowSum/rowSum2 (mu + 1.18/1.42 sigma
// bracket the 10% tail point with >19% margins; k_select falls back if not).
__global__ __launch_bounds__(256) void k_band(const _Float16* __restrict__ buf,
    const float* __restrict__ rowSum, const float* __restrict__ rowSum2,
    float* __restrict__ cand, int* __restrict__ cAboveG, float* __restrict__ sAbG,
    int* __restrict__ bandCntG, float* __restrict__ tau1G, float* __restrict__ tau2G){
  const int lane = threadIdx.x & 63;
  const int r = blockIdx.x * 4 + (threadIdx.x >> 6);
  const float mu = rowSum[r] * (1.f / NROW);
  float var = rowSum2[r] * (1.f / NROW) - mu * mu;
  const float sd = sqrtf(fmaxf(var, 1e-12f));
  const float t1 = mu + 1.18f * sd;
  const float t2 = mu + 1.42f * sd;
  const f16x8* src = (const f16x8*)(buf + (size_t)r * NROW);
  float* cd = cand + (size_t)r * BCAP;
  const unsigned long long below = (1ull << lane) - 1ull;
  int cAb = 0, wCnt = 0;
  float sAb = 0.f;
#pragma unroll 2
  for (int j = 0; j < 12; j++){
    f16x8 h8 = src[j * 64 + lane];
#pragma unroll
    for (int e = 0; e < 8; e++){
      float v = (float)h8[e];
      bool above = v > t2;
      bool band = (v > t1) && !above;
      if (above){ cAb++; sAb += v; }
      unsigned long long bm = __ballot(band);
      if (band){
        int p = wCnt + (int)__popcll(bm & below);
        if (p < BCAP) cd[p] = v;
      }
      wCnt += (int)__popcll(bm);
    }
  }
  cAb = waveAllRedI(cAb);
  sAb = waveAllRedF(sAb);
  if (lane == 0){
    cAboveG[r] = cAb; sAbG[r] = sAb; bandCntG[r] = wCnt;
    tau1G[r] = t1; tau2G[r] = t2;
  }
}

// -------- k_select: wave-per-row. Exact k1-th (tie-exact) on band + sMin + BP/BPd --------
__global__ __launch_bounds__(256) void k_select(const _Float16* __restrict__ buf,
    const unsigned char* __restrict__ lab, const int* __restrict__ cnt,
    const int* __restrict__ simIdx, const float* __restrict__ rowSum,
    const float* __restrict__ cand, const int* __restrict__ cAboveG,
    const float* __restrict__ sAbG, const int* __restrict__ bandCntG,
    const float* __restrict__ tau1G, const float* __restrict__ tau2G,
    float* __restrict__ BPg, float* __restrict__ BPdg){
  const int lane = threadIdx.x & 63;
  const int r = blockIdx.x * 4 + (threadIdx.x >> 6);
  const int myl = lab[r];
  const int n_sim = cnt[myl];
  const int n_dis = NROW - n_sim;
  if (n_sim == 0 || n_dis == 0) return;
  const int k1 = n_dis - (n_dis * 9) / 10;
  const int k2 = n_sim - (n_sim * 9) / 10;
  const int ns = (n_sim < 512) ? n_sim : 512;
  const _Float16* rowp = buf + (size_t)r * NROW;
  const int* ml = simIdx + myl * 512;
  const float t1 = tau1G[r], t2 = tau2G[r];

  // sim stats (gathers are L2-hot, ~31 elems)
  float simSum = 0.f, simSAb = 0.f;
  int simAb = 0, simBand = 0;
  for (int t = lane; t < ns; t += 64){
    float v = (float)rowp[ml[t]];
    simSum += v;
    if (v > t2){ simAb++; simSAb += v; }
    else if (v > t1) simBand++;
  }
  simSum = waveAllRedF(simSum); simSAb = waveAllRedF(simSAb);
  simAb = waveAllRedI(simAb); simBand = waveAllRedI(simBand);

  const int cAbD = cAboveG[r] - simAb;
  const int bandCnt = bandCntG[r];
  const int bandD = bandCnt - simBand;
  const int kr0 = k1 - cAbD;
  float dSum;

  if (kr0 >= 1 && kr0 <= bandD && bandCnt <= BCAP){
    const float* cd = cand + (size_t)r * BCAP;
    float pivW = 0.f; int gtW = 0; bool fw = false;
    for (int t = lane; t < bandCnt; t += 64){
      float vt = cd[t];
      int gt = 0, eq = 0;
      for (int j2 = 0; j2 < bandCnt; j2++){
        float vj = cd[j2];
        gt += (vj > vt); eq += (vj == vt);
      }
      for (int q = 0; q < ns; q++){            // subtract sim band members (exact)
        float vs = (float)rowp[ml[q]];
        if (vs > t1 && vs <= t2){ gt -= (vs > vt); eq -= (vs == vt); }
      }
      if (!fw && gt < kr0 && kr0 <= gt + eq){ pivW = vt; gtW = gt; fw = true; }
    }
    unsigned long long bm = __ballot(fw);
    int sl = __ffsll(bm) - 1;
    const float piv = __shfl(pivW, sl, 64);
    const int gtD = __shfl(gtW, sl, 64);
    float sg = 0.f, sgS = 0.f;
    for (int t = lane; t < bandCnt; t += 64){
      float v = cd[t];
      if (v > piv) sg += v;
    }
    for (int t = lane; t < ns; t += 64){
      float vs = (float)rowp[ml[t]];
      if (vs > t1 && vs <= t2 && vs > piv) sgS += vs;
    }
    sg = waveAllRedF(sg); sgS = waveAllRedF(sgS);
    dSum = (sAbG[r] - simSAb) + (sg - sgS) + (float)(kr0 - gtD) * piv;
  } else {
    // exact fallback: f16-key bisection over full row, sims subtracted
    const f16x8* src = (const f16x8*)rowp;
    unsigned lo = 0u, hi = 65535u;
    while (lo < hi){
      unsigned mid = (lo + hi) >> 1;
      int c = 0;
      for (int j = 0; j < 12; j++){
        f16x8 h8 = src[j * 64 + lane];
#pragma unroll
        for (int e = 0; e < 8; e++)
          if (key16_of(h8[e]) > mid) c++;
      }
      for (int t = lane; t < ns; t += 64)
        if (key16_of(rowp[ml[t]]) > mid) c--;
      c = waveAllRedI(c);
      if (c >= k1) lo = mid + 1; else hi = mid;
    }
    const float piv = key16_dec(lo);
    float sg = 0.f; int cg = 0;
    for (int j = 0; j < 12; j++){
      f16x8 h8 = src[j * 64 + lane];
#pragma unroll
      for (int e = 0; e < 8; e++){
        if (key16_of(h8[e]) > lo){ sg += (float)h8[e]; cg++; }
      }
    }
    for (int t = lane; t < ns; t += 64){
      _Float16 hv = rowp[ml[t]];
      if (key16_of(hv) > lo){ sg -= (float)hv; cg--; }
    }
    sg = waveAllRedF(sg); cg = waveAllRedI(cg);
    dSum = sg + (float)(k1 - cg) * piv;
  }

  // sMin: k2-th smallest similar (exact rank-count, ~31 elems)
  float pw = 0.f; int lw = 0; bool fw2 = false;
  for (int t = lane; t < ns; t += 64){
    float vt = (float)rowp[ml[t]];
    int lt = 0, eq = 0;
    for (int j2 = 0; j2 < ns; j2++){
      float vj = (float)rowp[ml[j2]];
      lt += (vj < vt); eq += (vj == vt);
    }
    if (!fw2 && lt < k2 && k2 <= lt + eq){ pw = vt; lw = lt; fw2 = true; }
  }
  unsigned long long bm3 = __ballot(fw2);
  int s3 = __ffsll(bm3) - 1;
  const float piv2 = __shfl(pw, s3, 64);
  const int ltS = __shfl(lw, s3, 64);
  float slt = 0.f;
  for (int t = lane; t < ns; t += 64){
    float vs = (float)rowp[ml[t]];
    if (vs < piv2) slt += vs;
  }
  slt = waveAllRedF(slt);
  const float sSum = slt + (float)(k2 - ltS) * piv2;

  if (lane == 0){
    const float sumDS = rowSum[r] - simSum;
    float meanS = fminf(fmaxf(simSum / fmaxf((float)n_sim, 1.f), 0.f), UBV);
    float meanDS = fminf(fmaxf(sumDS / fmaxf((float)n_dis, 1.f), 0.f), UBV);
    float dMax = fminf(fmaxf(dSum / fmaxf((float)k1, 1.f), 0.f), UBV);
    float sMin = fminf(fmaxf(sSum / fmaxf((float)k2, 1.f), 0.f), UBV);
    BPg[r] = meanS - (UBV - meanS) / UBV * fabsf(meanS - dMax);
    BPdg[r] = meanDS + meanDS / UBV * fabsf(meanDS - sMin);
  }
}

// -------- k_loss: wave-per-row, ONE mask-free softplus sweep + exact sim subtraction --------
__global__ __launch_bounds__(256) void k_loss(const _Float16* __restrict__ buf,
    const unsigned char* __restrict__ lab, const int* __restrict__ cnt,
    const int* __restrict__ simIdx, const float* __restrict__ BPg,
    const float* __restrict__ BPdg, float* __restrict__ accf, int* __restrict__ acci){
  const int lane = threadIdx.x & 63;
  const int r = blockIdx.x * 4 + (threadIdx.x >> 6);
  const int myl = lab[r];
  const int n_sim = cnt[myl];
  const int n_dis = NROW - n_sim;
  if (n_sim == 0 || n_dis == 0) return;
  const int ns = (n_sim < 512) ? n_sim : 512;
  const float BP = BPg[r], BPd = BPdg[r];
  const _Float16* rowp = buf + (size_t)r * NROW;
  const f16x8* src = (const f16x8*)rowp;
  const int* ml = simIdx + myl * 512;

  float an = 0.f, cn = 0.f;
#pragma unroll 2
  for (int j = 0; j < 12; j++){
    f16x8 h8 = src[j * 64 + lane];
#pragma unroll
    for (int e = 0; e < 8; e++){
      float v = (float)h8[e];
      float dcd = v - BPd;
      float f = ((v < BPd) ? C_COEF : 2.f * C_COEF) * dcd;
      float sp = softplus_f(-f);
      bool use = (v != BPd);
      an += use ? sp : 0.f;
      cn += use ? 1.f : 0.f;
    }
  }
  float anS = 0.f, cnS = 0.f, ap = 0.f, cp = 0.f;
  for (int t = lane; t < ns; t += 64){
    float v = (float)rowp[ml[t]];
    float dcd = v - BPd;
    float f = ((v < BPd) ? C_COEF : 2.f * C_COEF) * dcd;
    if (v != BPd){ anS += softplus_f(-f); cnS += 1.f; }   // bitwise-identical terms
    if (v != BP){
      float dc = v - BP;
      float f2 = ((v > BP) ? C_COEF : 2.f * C_COEF) * dc;
      ap += softplus_f(f2); cp += 1.f;
    }
  }
  an = waveAllRedF(an); cn = waveAllRedF(cn);
  anS = waveAllRedF(anS); cnS = waveAllRedF(cnS);
  ap = waveAllRedF(ap); cp = waveAllRedF(cp);
  if (lane == 0){
    atomicAdd(&accf[1], ap / fmaxf(cp, 1.f));
    atomicAdd(&accf[2], (an - anS) / fmaxf(cn - cnS, 1.f));
    atomicAdd(&acci[3], 1);
  }
}

__global__ void k_final(const float* __restrict__ accf, const int* __restrict__ acci,
                        float* __restrict__ out){
  if (threadIdx.x == 0 && blockIdx.x == 0){
    int c = acci[3];
    float posL = 0.f, navL = 0.f;
    if (c > 0){ posL = accf[1] / (float)c; navL = accf[2] / (float)c; }
    out[0] = posL + navL + 0.1f * (accf[0] / (float)(NROW * KDIM));
  }
}

extern "C" void kernel_launch(void* const* d_in, const int* in_sizes, int n_in,
                              void* d_out, int out_size, void* d_ws, size_t ws_size,
                              hipStream_t stream){
  const float* u = (const float*)d_in[0];
  const int* y = (const int*)d_in[1];
  char* ws = (char*)d_ws;
  float* accf = (float*)ws;                        // [0]=qSum [1]=posSum [2]=negSum
  int* acci = (int*)ws;                            // [3]=validCount
  int* cnt = (int*)(ws + 64);                      // 256 ints
  unsigned char* lab = (unsigned char*)(ws + 4096);        // 6144 B
  int* simIdx = (int*)(ws + 12288);                // 200*512*4 = 409600 -> 421888
  float* rowSum  = (float*)(ws + 421888);          // 24576
  float* rowSum2 = (float*)(ws + 446464);          // 24576
  int*   cAboveG = (int*)(ws + 471040);
  float* sAbG    = (float*)(ws + 495616);
  int*   bandCntG= (int*)(ws + 520192);
  float* tau1G   = (float*)(ws + 544768);
  float* tau2G   = (float*)(ws + 569344);
  float* BPg     = (float*)(ws + 593920);
  float* BPdg    = (float*)(ws + 618496);          // -> 643072
  _Float16* uhswz = (_Float16*)(ws + 643072);      // 1572864 -> 2215936
  _Float16* ibuf  = (_Float16*)(ws + 2215936);     // 75497472 -> 77713408
  float* cand     = (float*)(ws + 77713408);       // 6144*768*4 = 18874368 -> ~96.6 MB

  hipMemsetAsync(ws, 0, 4096, stream);                 // accf/acci + cnt
  hipMemsetAsync(ws + 421888, 0, 49152, stream);       // rowSum + rowSum2
  k_label<<<NROW, 256, 0, stream>>>(y, lab, cnt, simIdx);
  k_tanh<<<(NROW * 16) / 256, 256, 0, stream>>>(u, uhswz, accf);
  k_mm<<<dim3(48, 48), 256, 0, stream>>>(uhswz, ibuf, rowSum, rowSum2);
  k_band<<<NROW / 4, 256, 0, stream>>>(ibuf, rowSum, rowSum2, cand,
                                       cAboveG, sAbG, bandCntG, tau1G, tau2G);
  k_select<<<NROW / 4, 256, 0, stream>>>(ibuf, lab, cnt, simIdx, rowSum, cand,
                                         cAboveG, sAbG, bandCntG, tau1G, tau2G,
                                         BPg, BPdg);
  k_loss<<<NROW / 4, 256, 0, stream>>>(ibuf, lab, cnt, simIdx, BPg, BPdg, accf, acci);
  k_final<<<1, 64, 0, stream>>>(accf, acci, (float*)d_out);
}

// Round 10
// 410.832 us; speedup vs baseline: 1.4776x; 1.4776x over previous
//
#include <hip/hip_runtime.h>
#include <cstdint>

#define NROW 6144
#define KDIM 128
#define NLAB 200
#define C_COEF (-0.28719499063341177f)   /* -ln(99)/16 ; A_COEF = 2 exactly */
#define UBV 64.0f
#define BCAP 768

typedef _Float16 f16x8 __attribute__((ext_vector_type(8)));
typedef float f32x4 __attribute__((ext_vector_type(4)));
typedef __attribute__((address_space(1))) const void as1c_void;
typedef __attribute__((address_space(3))) void as3_void;

__device__ __forceinline__ float softplus_f(float x){
  return fmaxf(x, 0.f) + __logf(1.f + __expf(-fabsf(x)));
}
__device__ __forceinline__ float waveAllRedF(float v){
#pragma unroll
  for (int o = 32; o; o >>= 1) v += __shfl_down(v, o, 64);
  return __shfl(v, 0, 64);
}
__device__ __forceinline__ int waveAllRedI(int v){
#pragma unroll
  for (int o = 32; o; o >>= 1) v += __shfl_down(v, o, 64);
  return __shfl(v, 0, 64);
}
__device__ __forceinline__ unsigned key16_of(_Float16 h){
  unsigned short b = __builtin_bit_cast(unsigned short, h);
  return (b & 0x8000u) ? (unsigned)((unsigned short)~b) : (unsigned)(b | 0x8000u);
}
__device__ __forceinline__ float key16_dec(unsigned k){
  unsigned short b = (k & 0x8000u) ? (unsigned short)(k & 0x7FFFu)
                                   : (unsigned short)(~k & 0xFFFFu);
  return (float)__builtin_bit_cast(_Float16, b);
}

// ---------------- labels + per-label histogram + member lists ----------------
__global__ void k_label(const int* __restrict__ y, unsigned char* __restrict__ lab,
                        int* __restrict__ cnt, int* __restrict__ simIdx){
  const int row = blockIdx.x;
  const int t = threadIdx.x;
  if (t < NLAB){
    if (y[(size_t)row * NLAB + t] != 0){
      lab[row] = (unsigned char)t;
      int p = atomicAdd(&cnt[t], 1);
      if (p < 512) simIdx[t * 512 + p] = row;
    }
  }
}

// ---------------- tanh -> swizzled f16, + quantization-loss partial ----------------
__global__ __launch_bounds__(256) void k_tanh(const float* __restrict__ u,
    _Float16* __restrict__ uhswz, float* __restrict__ accf){
  const int tid = threadIdx.x;
  const int gid = blockIdx.x * 256 + tid;
  const int row = gid >> 4;
  const int h = gid & 15;
  const int g = h ^ (row & 7);
  const float* sp = u + (size_t)row * KDIM + g * 8;
  float q = 0.f;
  f16x8 o;
#pragma unroll
  for (int t = 0; t < 8; t++){
    float x = sp[t];
    float e2 = __expf(2.f * x);
    float th = 1.f - 2.f * __builtin_amdgcn_rcpf(e2 + 1.f);
    float sg = (th > 0.f) ? 1.f : ((th < 0.f) ? -1.f : 0.f);
    float d = th - sg;
    q += d * d;
    o[t] = (_Float16)th;
  }
  *(f16x8*)(uhswz + (size_t)row * KDIM + h * 8) = o;
  q = waveAllRedF(q);
  __shared__ float qb[4];
  if ((tid & 63) == 0) qb[tid >> 6] = q;
  __syncthreads();
  if (tid == 0) atomicAdd(&accf[0], qb[0] + qb[1] + qb[2] + qb[3]);
}

// ------- inner = uh @ uh^T -> f16 out; epilogue also emits per-row sum & sum^2 -------
__global__ __launch_bounds__(256) void k_mm(const _Float16* __restrict__ A,
    _Float16* __restrict__ out, float* __restrict__ rowSum,
    float* __restrict__ rowSum2){
  __shared__ __align__(16) _Float16 SH[2 * 128 * KDIM];
  _Float16* As = SH;
  _Float16* Bs = SH + 128 * KDIM;
  const int tid = threadIdx.x;
  const int wav = tid >> 6, lane = tid & 63;
  const int bj = blockIdx.x, bi = blockIdx.y;

  const char* Ag = (const char*)(A + (size_t)(bi * 128) * KDIM);
  const char* Bg = (const char*)(A + (size_t)(bj * 128) * KDIM);
  char* Asb = (char*)As;
  char* Bsb = (char*)Bs;
#pragma unroll
  for (int t = 0; t < 8; t++){
    const int ub = wav * 8192 + t * 1024;
    __builtin_amdgcn_global_load_lds((as1c_void*)(Ag + ub + lane * 16),
                                     (as3_void*)(Asb + ub), 16, 0, 0);
    __builtin_amdgcn_global_load_lds((as1c_void*)(Bg + ub + lane * 16),
                                     (as3_void*)(Bsb + ub), 16, 0, 0);
  }
  __syncthreads();

  const int quad = lane >> 4, l16 = lane & 15;
  const int wm = (wav >> 1) * 64, wn = (wav & 1) * 64;
  f32x4 acc[4][4];
#pragma unroll
  for (int im = 0; im < 4; im++)
#pragma unroll
    for (int in = 0; in < 4; in++)
      acc[im][in] = (f32x4){0.f, 0.f, 0.f, 0.f};

#pragma unroll
  for (int kb = 0; kb < 4; kb++){
    f16x8 af[4], bf[4];
#pragma unroll
    for (int i = 0; i < 4; i++){
      const int m = wm + i * 16 + l16;
      const int gidx = kb * 4 + quad;
      af[i] = *(const f16x8*)(Asb + m * 256 + ((gidx ^ (m & 7)) << 4));
      const int n = wn + i * 16 + l16;
      bf[i] = *(const f16x8*)(Bsb + n * 256 + ((gidx ^ (n & 7)) << 4));
    }
#pragma unroll
    for (int im = 0; im < 4; im++)
#pragma unroll
      for (int in = 0; in < 4; in++)
        acc[im][in] = __builtin_amdgcn_mfma_f32_16x16x32_f16(af[im], bf[in], acc[im][in], 0, 0, 0);
  }
  __syncthreads();

  _Float16* Cs = SH;
#pragma unroll
  for (int im = 0; im < 4; im++)
#pragma unroll
    for (int in = 0; in < 4; in++)
#pragma unroll
      for (int r = 0; r < 4; r++){
        const int rl = wm + im * 16 + quad * 4 + r;
        const int cl = wn + in * 16 + l16;
        Cs[rl * 132 + cl] = (_Float16)acc[im][in][r];
      }
  __syncthreads();

  _Float16* obase = out + (size_t)(bi * 128) * NROW + (size_t)bj * 128;
  const int s = tid & 15;
#pragma unroll
  for (int i = 0; i < 8; i++){
    const int r = (tid >> 4) + i * 16;
    f16x8 vv = *(const f16x8*)(Cs + r * 132 + s * 8);
    *(f16x8*)(obase + (size_t)r * NROW + s * 8) = vv;
    float a = 0.f, b = 0.f;
#pragma unroll
    for (int e = 0; e < 8; e++){
      float x = (float)vv[e];
      a += x; b += x * x;
    }
#pragma unroll
    for (int o = 8; o; o >>= 1){
      a += __shfl_down(a, o, 16);
      b += __shfl_down(b, o, 16);
    }
    if (s == 0){
      atomicAdd(&rowSum[bi * 128 + r], a);
      atomicAdd(&rowSum2[bi * 128 + r], b);
    }
  }
}

// -------- k_band: wave-per-row, one sweep; per-lane count + wave scan (no per-elem ballot) --------
__global__ __launch_bounds__(256) void k_band(const _Float16* __restrict__ buf,
    const float* __restrict__ rowSum, const float* __restrict__ rowSum2,
    float* __restrict__ cand, int* __restrict__ cAboveG, float* __restrict__ sAbG,
    int* __restrict__ bandCntG, float* __restrict__ tau1G, float* __restrict__ tau2G){
  const int lane = threadIdx.x & 63;
  const int r = blockIdx.x * 4 + (threadIdx.x >> 6);
  const float mu = rowSum[r] * (1.f / NROW);
  float var = rowSum2[r] * (1.f / NROW) - mu * mu;
  const float sd = sqrtf(fmaxf(var, 1e-12f));
  const float t1 = mu + 1.18f * sd;
  const float t2 = mu + 1.42f * sd;
  const f16x8* src = (const f16x8*)(buf + (size_t)r * NROW);
  f16x8 h[12];
  int cAb = 0, cntL = 0;
  float sAb = 0.f;
#pragma unroll
  for (int j = 0; j < 12; j++){
    h[j] = src[j * 64 + lane];
#pragma unroll
    for (int e = 0; e < 8; e++){
      float v = (float)h[j][e];
      bool above = v > t2;
      cAb += above;
      sAb += above ? v : 0.f;
      cntL += (v > t1) && !above;
    }
  }
  int incl = cntL;
#pragma unroll
  for (int o = 1; o < 64; o <<= 1){ int x = __shfl_up(incl, o, 64); if (lane >= o) incl += x; }
  const int total = __shfl(incl, 63, 64);
  int pos = incl - cntL;                           // exclusive base
  float* cd = cand + (size_t)r * BCAP;
#pragma unroll
  for (int j = 0; j < 12; j++)
#pragma unroll
    for (int e = 0; e < 8; e++){
      float v = (float)h[j][e];
      if (v > t1 && v <= t2){
        if (pos < BCAP) cd[pos] = v;
        pos++;
      }
    }
  cAb = waveAllRedI(cAb);
  sAb = waveAllRedF(sAb);
  if (lane == 0){
    cAboveG[r] = cAb; sAbG[r] = sAb; bandCntG[r] = total;
    tau1G[r] = t1; tau2G[r] = t2;
  }
}

// -------- k_select: exact tie-aware k1-th on band (register candidates, shuffle sims) --------
__global__ __launch_bounds__(256) void k_select(const _Float16* __restrict__ buf,
    const unsigned char* __restrict__ lab, const int* __restrict__ cnt,
    const int* __restrict__ simIdx, const float* __restrict__ rowSum,
    const float* __restrict__ cand, const int* __restrict__ cAboveG,
    const float* __restrict__ sAbG, const int* __restrict__ bandCntG,
    const float* __restrict__ tau1G, const float* __restrict__ tau2G,
    float* __restrict__ BPg, float* __restrict__ BPdg){
  const int lane = threadIdx.x & 63;
  const int r = blockIdx.x * 4 + (threadIdx.x >> 6);
  const int myl = lab[r];
  const int n_sim = cnt[myl];
  const int n_dis = NROW - n_sim;
  if (n_sim == 0 || n_dis == 0) return;
  const int k1 = n_dis - (n_dis * 9) / 10;
  const int k2 = n_sim - (n_sim * 9) / 10;
  const int ns = (n_sim < 512) ? n_sim : 512;
  const int nblk = (ns + 63) >> 6;                 // wave-uniform
  const _Float16* rowp = buf + (size_t)r * NROW;
  const int* ml = simIdx + myl * 512;
  const float t1 = tau1G[r], t2 = tau2G[r];

  // sim values -> registers (slot i holds member lane+64*i)
  float sv[8];
#pragma unroll
  for (int i = 0; i < 8; i++){
    int t = lane + 64 * i;
    sv[i] = (i < nblk && t < ns) ? (float)rowp[ml[t]] : 0.f;
  }
  float simSum = 0.f, simSAb = 0.f;
  int simAb = 0, simBand = 0;
#pragma unroll
  for (int i = 0; i < 8; i++){
    int t = lane + 64 * i;
    if (i < nblk && t < ns){
      float v = sv[i];
      simSum += v;
      if (v > t2){ simAb++; simSAb += v; }
      else if (v > t1) simBand++;
    }
  }
  simSum = waveAllRedF(simSum); simSAb = waveAllRedF(simSAb);
  simAb = waveAllRedI(simAb); simBand = waveAllRedI(simBand);

  const int cAbD = cAboveG[r] - simAb;
  const int bandCnt = bandCntG[r];
  const int bandD = bandCnt - simBand;
  const int kr0 = k1 - cAbD;
  float dSum;

  if (kr0 >= 1 && kr0 <= bandD && bandCnt <= BCAP){
    const float* cd = cand + (size_t)r * BCAP;
    const int nk = (bandCnt + 63) >> 6;            // <= 12
    float vt[12]; int gt[12], eq[12];
#pragma unroll
    for (int k = 0; k < 12; k++){
      int t = k * 64 + lane;
      vt[k] = (k < nk && t < bandCnt) ? cd[t] : 1e30f;
      gt[k] = 0; eq[k] = 0;
    }
#pragma unroll 4
    for (int j2 = 0; j2 < bandCnt; j2++){
      float vj = cd[j2];
#pragma unroll
      for (int k = 0; k < 12; k++){
        if (k < nk){ gt[k] += (vj > vt[k]); eq[k] += (vj == vt[k]); }
      }
    }
    // subtract sim band members (convergent shuffle broadcast)
#pragma unroll
    for (int i = 0; i < 8; i++){
      if (i >= nblk) break;
      int lim = ns - 64 * i; if (lim > 64) lim = 64;
      float svb = sv[i];
      for (int o = 0; o < lim; o++){
        float vs = __shfl(svb, o, 64);
        if (vs > t1 && vs <= t2){
#pragma unroll
          for (int k = 0; k < 12; k++){
            if (k < nk){ gt[k] -= (vs > vt[k]); eq[k] -= (vs == vt[k]); }
          }
        }
      }
    }
    float pivW = 0.f; int gtW = 0; bool fw = false;
#pragma unroll
    for (int k = 0; k < 12; k++){
      int t = k * 64 + lane;
      if (k < nk && t < bandCnt && !fw && gt[k] < kr0 && kr0 <= gt[k] + eq[k]){
        pivW = vt[k]; gtW = gt[k]; fw = true;
      }
    }
    unsigned long long bm = __ballot(fw);
    int sl = __ffsll(bm) - 1;
    const float piv = __shfl(pivW, sl, 64);
    const int gtD = __shfl(gtW, sl, 64);
    float sg = 0.f, sgS = 0.f;
#pragma unroll
    for (int k = 0; k < 12; k++){
      int t = k * 64 + lane;
      if (k < nk && t < bandCnt && vt[k] > piv) sg += vt[k];
    }
#pragma unroll
    for (int i = 0; i < 8; i++){
      int t = lane + 64 * i;
      if (i < nblk && t < ns){
        float vs = sv[i];
        if (vs > t1 && vs <= t2 && vs > piv) sgS += vs;
      }
    }
    sg = waveAllRedF(sg); sgS = waveAllRedF(sgS);
    dSum = (sAbG[r] - simSAb) + (sg - sgS) + (float)(kr0 - gtD) * piv;
  } else {
    // exact fallback: f16-key bisection over full row, sims subtracted (rare)
    const f16x8* src = (const f16x8*)rowp;
    unsigned lo = 0u, hi = 65535u;
    while (lo < hi){
      unsigned mid = (lo + hi) >> 1;
      int c = 0;
      for (int j = 0; j < 12; j++){
        f16x8 h8 = src[j * 64 + lane];
#pragma unroll
        for (int e = 0; e < 8; e++)
          if (key16_of(h8[e]) > mid) c++;
      }
#pragma unroll
      for (int i = 0; i < 8; i++){
        int t = lane + 64 * i;
        if (i < nblk && t < ns && key16_of((_Float16)sv[i]) > mid) c--;
      }
      c = waveAllRedI(c);
      if (c >= k1) lo = mid + 1; else hi = mid;
    }
    const float piv = key16_dec(lo);
    float sg = 0.f; int cg = 0;
    for (int j = 0; j < 12; j++){
      f16x8 h8 = src[j * 64 + lane];
#pragma unroll
      for (int e = 0; e < 8; e++){
        if (key16_of(h8[e]) > lo){ sg += (float)h8[e]; cg++; }
      }
    }
#pragma unroll
    for (int i = 0; i < 8; i++){
      int t = lane + 64 * i;
      if (i < nblk && t < ns && key16_of((_Float16)sv[i]) > lo){ sg -= sv[i]; cg--; }
    }
    sg = waveAllRedF(sg); cg = waveAllRedI(cg);
    dSum = sg + (float)(k1 - cg) * piv;
  }

  // sMin: exact rank-count on sim registers via convergent shuffles
  int lt2[8], eq2[8];
#pragma unroll
  for (int i = 0; i < 8; i++){ lt2[i] = 0; eq2[i] = 0; }
#pragma unroll
  for (int ii = 0; ii < 8; ii++){
    if (ii >= nblk) break;
    int lim = ns - 64 * ii; if (lim > 64) lim = 64;
    float svb = sv[ii];
    for (int o = 0; o < lim; o++){
      float vj = __shfl(svb, o, 64);
#pragma unroll
      for (int i = 0; i < 8; i++){
        if (i < nblk){ lt2[i] += (vj < sv[i]); eq2[i] += (vj == sv[i]); }
      }
    }
  }
  float pw = 0.f; int lw = 0; bool fw2 = false;
#pragma unroll
  for (int i = 0; i < 8; i++){
    int t = lane + 64 * i;
    if (i < nblk && t < ns && !fw2 && lt2[i] < k2 && k2 <= lt2[i] + eq2[i]){
      pw = sv[i]; lw = lt2[i]; fw2 = true;
    }
  }
  unsigned long long bm3 = __ballot(fw2);
  int s3 = __ffsll(bm3) - 1;
  const float piv2 = __shfl(pw, s3, 64);
  const int ltS = __shfl(lw, s3, 64);
  float slt = 0.f;
#pragma unroll
  for (int i = 0; i < 8; i++){
    int t = lane + 64 * i;
    if (i < nblk && t < ns && sv[i] < piv2) slt += sv[i];
  }
  slt = waveAllRedF(slt);
  const float sSum = slt + (float)(k2 - ltS) * piv2;

  if (lane == 0){
    const float sumDS = rowSum[r] - simSum;
    float meanS = fminf(fmaxf(simSum / fmaxf((float)n_sim, 1.f), 0.f), UBV);
    float meanDS = fminf(fmaxf(sumDS / fmaxf((float)n_dis, 1.f), 0.f), UBV);
    float dMax = fminf(fmaxf(dSum / fmaxf((float)k1, 1.f), 0.f), UBV);
    float sMin = fminf(fmaxf(sSum / fmaxf((float)k2, 1.f), 0.f), UBV);
    BPg[r] = meanS - (UBV - meanS) / UBV * fabsf(meanS - dMax);
    BPdg[r] = meanDS + meanDS / UBV * fabsf(meanDS - sMin);
  }
}

// -------- k_loss: one sweep; per-row OUTPUT (no contended atomics) --------
__global__ __launch_bounds__(256) void k_loss(const _Float16* __restrict__ buf,
    const unsigned char* __restrict__ lab, const int* __restrict__ cnt,
    const int* __restrict__ simIdx, const float* __restrict__ BPg,
    const float* __restrict__ BPdg, float* __restrict__ rowPos,
    float* __restrict__ rowNeg, int* __restrict__ rowValid){
  const int lane = threadIdx.x & 63;
  const int r = blockIdx.x * 4 + (threadIdx.x >> 6);
  const int myl = lab[r];
  const int n_sim = cnt[myl];
  const int n_dis = NROW - n_sim;
  if (n_sim == 0 || n_dis == 0){
    if (lane == 0){ rowPos[r] = 0.f; rowNeg[r] = 0.f; rowValid[r] = 0; }
    return;
  }
  const int ns = (n_sim < 512) ? n_sim : 512;
  const float BP = BPg[r], BPd = BPdg[r];
  const _Float16* rowp = buf + (size_t)r * NROW;
  const f16x8* src = (const f16x8*)rowp;
  const int* ml = simIdx + myl * 512;

  float an = 0.f, cn = 0.f;
#pragma unroll 3
  for (int j = 0; j < 12; j++){
    f16x8 h8 = src[j * 64 + lane];
#pragma unroll
    for (int e = 0; e < 8; e++){
      float v = (float)h8[e];
      float dcd = v - BPd;
      float f = ((v < BPd) ? C_COEF : 2.f * C_COEF) * dcd;
      float sp = softplus_f(-f);
      bool use = (v != BPd);
      an += use ? sp : 0.f;
      cn += use ? 1.f : 0.f;
    }
  }
  float anS = 0.f, cnS = 0.f, ap = 0.f, cp = 0.f;
  for (int t = lane; t < ns; t += 64){
    float v = (float)rowp[ml[t]];
    float dcd = v - BPd;
    float f = ((v < BPd) ? C_COEF : 2.f * C_COEF) * dcd;
    if (v != BPd){ anS += softplus_f(-f); cnS += 1.f; }   // bitwise-identical terms
    if (v != BP){
      float dc = v - BP;
      float f2 = ((v > BP) ? C_COEF : 2.f * C_COEF) * dc;
      ap += softplus_f(f2); cp += 1.f;
    }
  }
  an = waveAllRedF(an); cn = waveAllRedF(cn);
  anS = waveAllRedF(anS); cnS = waveAllRedF(cnS);
  ap = waveAllRedF(ap); cp = waveAllRedF(cp);
  if (lane == 0){
    rowPos[r] = ap / fmaxf(cp, 1.f);
    rowNeg[r] = (an - anS) / fmaxf(cn - cnS, 1.f);
    rowValid[r] = 1;
  }
}

// -------- k_final: single-block reduction over per-row results --------
__global__ __launch_bounds__(256) void k_final(const float* __restrict__ accf,
    const float* __restrict__ rowPos, const float* __restrict__ rowNeg,
    const int* __restrict__ rowValid, float* __restrict__ out){
  __shared__ float sb[12];
  const int tid = threadIdx.x, lane = tid & 63, wav = tid >> 6;
  float p = 0.f, n = 0.f, c = 0.f;
  for (int t = tid; t < NROW; t += 256){
    p += rowPos[t]; n += rowNeg[t]; c += (float)rowValid[t];
  }
  p = waveAllRedF(p); n = waveAllRedF(n); c = waveAllRedF(c);
  if (lane == 0){ sb[wav] = p; sb[4 + wav] = n; sb[8 + wav] = c; }
  __syncthreads();
  if (tid == 0){
    float P = sb[0] + sb[1] + sb[2] + sb[3];
    float N = sb[4] + sb[5] + sb[6] + sb[7];
    float C = sb[8] + sb[9] + sb[10] + sb[11];
    float posL = 0.f, navL = 0.f;
    if (C > 0.f){ posL = P / C; navL = N / C; }
    out[0] = posL + navL + 0.1f * (accf[0] / (float)(NROW * KDIM));
  }
}

extern "C" void kernel_launch(void* const* d_in, const int* in_sizes, int n_in,
                              void* d_out, int out_size, void* d_ws, size_t ws_size,
                              hipStream_t stream){
  const float* u = (const float*)d_in[0];
  const int* y = (const int*)d_in[1];
  char* ws = (char*)d_ws;
  float* accf = (float*)ws;                        // [0]=qSum
  int* cnt = (int*)(ws + 64);                      // 256 ints
  unsigned char* lab = (unsigned char*)(ws + 4096);        // 6144 B
  int* simIdx = (int*)(ws + 12288);                // 200*512*4 = 409600 -> 421888
  float* rowSum  = (float*)(ws + 421888);          // 24576
  float* rowSum2 = (float*)(ws + 446464);          // 24576
  int*   cAboveG = (int*)(ws + 471040);
  float* sAbG    = (float*)(ws + 495616);
  int*   bandCntG= (int*)(ws + 520192);
  float* tau1G   = (float*)(ws + 544768);
  float* tau2G   = (float*)(ws + 569344);
  float* BPg     = (float*)(ws + 593920);
  float* BPdg    = (float*)(ws + 618496);
  float* rowPos  = (float*)(ws + 643072);
  float* rowNeg  = (float*)(ws + 667648);
  int*   rowValid= (int*)(ws + 692224);            // -> 716800
  _Float16* uhswz = (_Float16*)(ws + 716800);      // +1572864 -> 2289664
  _Float16* ibuf  = (_Float16*)(ws + 2289664);     // +75497472 -> 77787136
  float* cand     = (float*)(ws + 77787136);       // +18874368 -> ~96.7 MB

  hipMemsetAsync(ws, 0, 4096, stream);                 // accf + cnt
  hipMemsetAsync(ws + 421888, 0, 49152, stream);       // rowSum + rowSum2
  k_label<<<NROW, 256, 0, stream>>>(y, lab, cnt, simIdx);
  k_tanh<<<(NROW * 16) / 256, 256, 0, stream>>>(u, uhswz, accf);
  k_mm<<<dim3(48, 48), 256, 0, stream>>>(uhswz, ibuf, rowSum, rowSum2);
  k_band<<<NROW / 4, 256, 0, stream>>>(ibuf, rowSum, rowSum2, cand,
                                       cAboveG, sAbG, bandCntG, tau1G, tau2G);
  k_select<<<NROW / 4, 256, 0, stream>>>(ibuf, lab, cnt, simIdx, rowSum, cand,
                                         cAboveG, sAbG, bandCntG, tau1G, tau2G,
                                         BPg, BPdg);
  k_loss<<<NROW / 4, 256, 0, stream>>>(ibuf, lab, cnt, simIdx, BPg, BPdg,
                                       rowPos, rowNeg, rowValid);
  k_final<<<1, 256, 0, stream>>>(accf, rowPos, rowNeg, rowValid, (float*)d_out);
}